// Round 1
// baseline (315.099 us; speedup 1.0000x reference)
//
#include <hip/hip_runtime.h>
#include <hip/hip_bf16.h>

#define N_NODES 50000
#define E_EDGES 800000
#define IN_DIM  128
#define OUT_DIM 64

// ---------------------------------------------------------------------------
// Kernel A: z = h @ W_fc^T + b_fc  (N x 64), plus per-node attention scalars
//   s1[n] = dot(z[n], W_att[0:64]), s2[n] = dot(z[n], W_att[64:128])
// One wave per node; lane = output dim (64 lanes == 64 outs).
// W_fc staged transposed in LDS (wt[k][o], padded to 65 -> conflict-free).
// ---------------------------------------------------------------------------
__global__ __launch_bounds__(256) void gat_fc(
    const float* __restrict__ h,
    const float* __restrict__ Wfc,
    const float* __restrict__ bfc,
    const float* __restrict__ Watt,
    float* __restrict__ z,
    float* __restrict__ s1,
    float* __restrict__ s2)
{
    __shared__ float wt[IN_DIM][OUT_DIM + 1];  // +1 pad: stride 65 breaks bank aliasing

    // Coalesced global read of Wfc (row-major [o][k]), scattered padded LDS write.
    for (int i = threadIdx.x; i < OUT_DIM * IN_DIM; i += 256) {
        int o = i / IN_DIM;
        int k = i - o * IN_DIM;
        wt[k][o] = Wfc[i];
    }
    __syncthreads();

    const int lane  = threadIdx.x & 63;
    const int wave  = threadIdx.x >> 6;
    const int gwave = blockIdx.x * 4 + wave;
    const int nwav  = gridDim.x * 4;

    const float bias = bfc[lane];
    const float w1l  = Watt[lane];
    const float w2l  = Watt[OUT_DIM + lane];

    for (int n = gwave; n < N_NODES; n += nwav) {
        const float* hr = h + (size_t)n * IN_DIM;
        float acc = bias;
        #pragma unroll
        for (int k = 0; k < IN_DIM; k += 4) {
            // wave-uniform 16B load (L1 broadcast)
            float4 hk = *(const float4*)(hr + k);
            acc += hk.x * wt[k + 0][lane];
            acc += hk.y * wt[k + 1][lane];
            acc += hk.z * wt[k + 2][lane];
            acc += hk.w * wt[k + 3][lane];
        }
        z[(size_t)n * OUT_DIM + lane] = acc;

        // fused attention scalars: butterfly reduce across the 64-lane wave
        float p1 = acc * w1l;
        float p2 = acc * w2l;
        #pragma unroll
        for (int off = 32; off > 0; off >>= 1) {
            p1 += __shfl_xor(p1, off, 64);
            p2 += __shfl_xor(p2, off, 64);
        }
        if (lane == 0) { s1[n] = p1; s2[n] = p2; }
    }
}

// ---------------------------------------------------------------------------
// Kernel B: per-edge scatter-accumulate.
//   att = leaky_relu(s1[src] + s2[dst] + b_att, 0.01)
//   out[dst][:] += z[src][:] * att      (fp32 HW atomics)
// One wave per edge; lane = feature dim. adj/s1/s2 loads are wave-uniform,
// z load is a coalesced 256B row.
// ---------------------------------------------------------------------------
__global__ __launch_bounds__(256) void gat_edge(
    const int*   __restrict__ adj,
    const float* __restrict__ z,
    const float* __restrict__ s1,
    const float* __restrict__ s2,
    const float* __restrict__ batt,
    float* __restrict__ out)
{
    const int lane  = threadIdx.x & 63;
    const int gwave = (blockIdx.x * 256 + threadIdx.x) >> 6;
    const int nwav  = (gridDim.x * 256) >> 6;
    const float ba  = batt[0];

    for (int e = gwave; e < E_EDGES; e += nwav) {
        const int src = adj[e];
        const int dst = adj[E_EDGES + e];
        const float logit = s1[src] + s2[dst] + ba;
        const float att   = (logit > 0.0f) ? logit : 0.01f * logit;
        const float val   = z[(size_t)src * OUT_DIM + lane] * att;
        unsafeAtomicAdd(&out[(size_t)dst * OUT_DIM + lane], val);
    }
}

extern "C" void kernel_launch(void* const* d_in, const int* in_sizes, int n_in,
                              void* d_out, int out_size, void* d_ws, size_t ws_size,
                              hipStream_t stream)
{
    const int*   adj  = (const int*)  d_in[0];   // (2, E)
    const float* h    = (const float*)d_in[1];   // (N, 128)
    const float* Wfc  = (const float*)d_in[2];   // (64, 128)
    const float* bfc  = (const float*)d_in[3];   // (64,)
    const float* Watt = (const float*)d_in[4];   // (1, 128)
    const float* batt = (const float*)d_in[5];   // (1,)
    float* out = (float*)d_out;                  // (N, 64)

    // workspace layout: z (N*64 f32) | s1 (N) | s2 (N)
    float* z  = (float*)d_ws;
    float* s1 = z + (size_t)N_NODES * OUT_DIM;
    float* s2 = s1 + N_NODES;

    // out is re-poisoned to 0xAA before every timed launch -> zero it here.
    hipMemsetAsync(d_out, 0, (size_t)N_NODES * OUT_DIM * sizeof(float), stream);

    gat_fc<<<1024, 256, 0, stream>>>(h, Wfc, bfc, Watt, z, s1, s2);
    gat_edge<<<4096, 256, 0, stream>>>(adj, z, s1, s2, batt, out);
}